// Round 1
// baseline (59.566 us; speedup 1.0000x reference)
//
#include <hip/hip_runtime.h>

#define B_ 8
#define N_ 256
#define D_ 512
#define TI 4   // query rows per block

// grid = B_ * (N_/TI) = 512 blocks, 256 threads (4 waves)
__global__ __launch_bounds__(256, 2)
void manh_attn_kernel(const float* __restrict__ q,
                      const float* __restrict__ k,
                      const float* __restrict__ v,
                      float* __restrict__ out)
{
    __shared__ float s_mat[TI][N_];   // scores, then normalized attn weights

    const int t   = threadIdx.x;
    const int bid = blockIdx.x;
    const int b   = bid >> 6;          // 64 i-tiles per batch
    const int i0  = (bid & 63) * TI;

    // ---------------- Phase A: L1 distance, column j = t ----------------
    // k row streamed per-thread (each 64B line used by 4 consecutive quads);
    // q rows are wave-uniform addresses -> scalar loads on the SMEM pipe.
    const float* __restrict__ krow  = k + ((size_t)(b * N_ + t)) * D_;
    const float* __restrict__ qbase = q + ((size_t)(b * N_ + i0)) * D_;

    float acc0 = 0.f, acc1 = 0.f, acc2 = 0.f, acc3 = 0.f;

    #pragma unroll 4
    for (int d = 0; d < D_; d += 4) {
        const float4 kv = *(const float4*)(krow + d);
        const float4 q0 = *(const float4*)(qbase + d);
        const float4 q1 = *(const float4*)(qbase + D_ + d);
        const float4 q2 = *(const float4*)(qbase + 2 * D_ + d);
        const float4 q3 = *(const float4*)(qbase + 3 * D_ + d);
        acc0 += (fabsf(q0.x - kv.x) + fabsf(q0.y - kv.y)) + (fabsf(q0.z - kv.z) + fabsf(q0.w - kv.w));
        acc1 += (fabsf(q1.x - kv.x) + fabsf(q1.y - kv.y)) + (fabsf(q1.z - kv.z) + fabsf(q1.w - kv.w));
        acc2 += (fabsf(q2.x - kv.x) + fabsf(q2.y - kv.y)) + (fabsf(q2.z - kv.z) + fabsf(q2.w - kv.w));
        acc3 += (fabsf(q3.x - kv.x) + fabsf(q3.y - kv.y)) + (fabsf(q3.z - kv.z) + fabsf(q3.w - kv.w));
    }

    s_mat[0][t] = -acc0;
    s_mat[1][t] = -acc1;
    s_mat[2][t] = -acc2;
    s_mat[3][t] = -acc3;
    __syncthreads();

    // ---------------- Phase B: softmax, one wave per row ----------------
    {
        const int w = t >> 6;          // wave id == local row
        const int l = t & 63;
        float v0 = s_mat[w][l];
        float v1 = s_mat[w][l + 64];
        float v2 = s_mat[w][l + 128];
        float v3 = s_mat[w][l + 192];
        float m = fmaxf(fmaxf(v0, v1), fmaxf(v2, v3));
        #pragma unroll
        for (int off = 32; off; off >>= 1) m = fmaxf(m, __shfl_xor(m, off));
        const float c = 1.4426950408889634f;
        float e0 = exp2f((v0 - m) * c);
        float e1 = exp2f((v1 - m) * c);
        float e2 = exp2f((v2 - m) * c);
        float e3 = exp2f((v3 - m) * c);
        float s = (e0 + e1) + (e2 + e3);
        #pragma unroll
        for (int off = 32; off; off >>= 1) s += __shfl_xor(s, off);
        const float r = 1.0f / s;
        s_mat[w][l]       = e0 * r;
        s_mat[w][l + 64]  = e1 * r;
        s_mat[w][l + 128] = e2 * r;
        s_mat[w][l + 192] = e3 * r;
    }
    __syncthreads();

    // ---------------- Phase C: out = attn @ v ----------------
    // thread owns d-quad (t&127)*4 for rows {i0+2ig, i0+2ig+1}
    const int ig = t >> 7;
    const int d0 = (t & 127) * 4;
    const float* __restrict__ vbase = v + ((size_t)b * N_) * D_ + d0;
    const float* __restrict__ wr0 = &s_mat[2 * ig][0];
    const float* __restrict__ wr1 = &s_mat[2 * ig + 1][0];

    float4 a0 = make_float4(0.f, 0.f, 0.f, 0.f);
    float4 a1 = make_float4(0.f, 0.f, 0.f, 0.f);

#define PV_STEP(W0, W1, VV)                                     \
    a0.x += (W0) * (VV).x; a0.y += (W0) * (VV).y;               \
    a0.z += (W0) * (VV).z; a0.w += (W0) * (VV).w;               \
    a1.x += (W1) * (VV).x; a1.y += (W1) * (VV).y;               \
    a1.z += (W1) * (VV).z; a1.w += (W1) * (VV).w;

    #pragma unroll 2
    for (int j = 0; j < N_; j += 4) {
        const float4 w0 = *(const float4*)(wr0 + j);
        const float4 w1 = *(const float4*)(wr1 + j);
        const float4 vv0 = *(const float4*)(vbase + (size_t)(j + 0) * D_);
        const float4 vv1 = *(const float4*)(vbase + (size_t)(j + 1) * D_);
        const float4 vv2 = *(const float4*)(vbase + (size_t)(j + 2) * D_);
        const float4 vv3 = *(const float4*)(vbase + (size_t)(j + 3) * D_);
        PV_STEP(w0.x, w1.x, vv0)
        PV_STEP(w0.y, w1.y, vv1)
        PV_STEP(w0.z, w1.z, vv2)
        PV_STEP(w0.w, w1.w, vv3)
    }
#undef PV_STEP

    float* op = out + ((size_t)(b * N_ + i0 + 2 * ig)) * D_ + d0;
    *(float4*)op        = a0;
    *(float4*)(op + D_) = a1;
}

extern "C" void kernel_launch(void* const* d_in, const int* in_sizes, int n_in,
                              void* d_out, int out_size, void* d_ws, size_t ws_size,
                              hipStream_t stream)
{
    const float* q = (const float*)d_in[0];
    const float* k = (const float*)d_in[1];
    const float* v = (const float*)d_in[2];
    float* out = (float*)d_out;

    manh_attn_kernel<<<dim3(B_ * (N_ / TI)), dim3(256), 0, stream>>>(q, k, v, out);
}